// Round 3
// baseline (764.932 us; speedup 1.0000x reference)
//
#include <hip/hip_runtime.h>

#define IN_DIM 384
#define HID    128
#define NPB    256            // nodes per bucket (dstLocal fits in 8 bits)
#define BCAP   16384          // fixed bucket capacity (max fill ~8.7k, 1.9x margin)
#define LCAP   10240          // LDS-resident bucket capacity (40KB)

#define AS1 __attribute__((address_space(1)))
#define AS3 __attribute__((address_space(3)))

typedef _Float16 half8 __attribute__((ext_vector_type(8)));
typedef _Float16 half2t __attribute__((ext_vector_type(2)));
typedef __fp16 fp16x2 __attribute__((ext_vector_type(2)));
typedef float floatx4 __attribute__((ext_vector_type(4)));

// ---------------- utility ----------------
__global__ void zero_i32(int* __restrict__ p, int n) {
  int i = blockIdx.x * 256 + threadIdx.x;
  if (i < n) p[i] = 0;
}

// ---------------- phase 1: partition edges into fixed-capacity coarse buckets -------
// 8192 edges/block, 512 threads (8 waves); packed value = (dstLocal << 17) | src
// Also grid-stride zeroes the sa/sb accumulator (needed by agg_score_g16 atomics).
__global__ __launch_bounds__(512) void partition_kernel(
    const int* __restrict__ src, const int* __restrict__ dst, int E, int nB,
    int* __restrict__ bCur, unsigned* __restrict__ bucketData,
    float* __restrict__ sab, int sabN) {
  __shared__ int hist[391];
  __shared__ int gbase[391];
  const int t = threadIdx.x;
  const int b0 = blockIdx.x * 8192;

  for (int i = blockIdx.x * 512 + t; i < sabN; i += gridDim.x * 512) sab[i] = 0.f;

  for (int i = t; i < nB; i += 512) hist[i] = 0;
  __syncthreads();
#pragma unroll
  for (int i = 0; i < 16; ++i) {
    int e = b0 + i * 512 + t;
    if (e < E) atomicAdd(&hist[dst[e] >> 8], 1);
  }
  __syncthreads();
  for (int i = t; i < nB; i += 512) {
    int h = hist[i];
    gbase[i] = h ? (i * BCAP + atomicAdd(&bCur[i], h)) : 0;
    hist[i] = 0;
  }
  __syncthreads();
#pragma unroll
  for (int i = 0; i < 16; ++i) {
    int e = b0 + i * 512 + t;
    if (e < E) {
      int d = dst[e];
      int b = d >> 8;
      int r = atomicAdd(&hist[b], 1);
      bucketData[gbase[b] + r] = ((unsigned)(d & 255) << 17) | (unsigned)src[e];
    }
  }
}

// ---------------- phase 2: per-bucket node histogram + scan + scatter ----------------
__global__ __launch_bounds__(1024) void node_sort3(
    const unsigned* __restrict__ bucketData, const int* __restrict__ bCur,
    int N, int* __restrict__ sorted_src, int* __restrict__ rs, int* __restrict__ re) {
  extern __shared__ unsigned sdata[];          // LCAP entries
  __shared__ int hist[NPB];
  __shared__ int s[NPB];
  __shared__ int cur[NPB];
  const int b = blockIdx.x;
  const int t = threadIdx.x;
  const int start = b * BCAP;
  const int fill = bCur[b];
  if (t < NPB) hist[t] = 0;
  __syncthreads();
  for (int i = t; i < fill; i += 1024) {
    unsigned d = bucketData[start + i];
    if (i < LCAP) sdata[i] = d;
    atomicAdd(&hist[d >> 17], 1);
  }
  __syncthreads();
  int v = 0;
  if (t < NPB) { v = hist[t]; s[t] = v; }
  __syncthreads();
  for (int off = 1; off < NPB; off <<= 1) {
    int y = (t < NPB && t >= off) ? s[t - off] : 0;
    __syncthreads();
    if (t < NPB) s[t] += y;
    __syncthreads();
  }
  if (t < NPB) {
    int excl = s[t] - v;
    const int node = b * NPB + t;
    if (node < N) {
      rs[node] = start + excl;
      re[node] = start + excl + v;
    }
    cur[t] = start + excl;
  }
  __syncthreads();
  for (int i = t; i < fill; i += 1024) {
    unsigned d = (i < LCAP) ? sdata[i] : bucketData[start + i];
    int p = atomicAdd(&cur[d >> 17], 1);
    sorted_src[p] = (int)(d & 0x1FFFF);
  }
}

// ---------------- weight pack: W[K][128] fp32 -> per-lane MFMA B-fragment order ------
__global__ void pack_w2(const float* __restrict__ Wl, const float* __restrict__ Wr,
                        _Float16* __restrict__ Bp) {
  const float* __restrict__ W = blockIdx.z ? Wr : Wl;
  const int tn = blockIdx.x;
  const int ks = blockIdx.y;
  const int KS = gridDim.y;
  const int lane = threadIdx.x;
  const int n = tn * 16 + (lane & 15);
  const int kb = ks * 32 + (lane >> 4) * 8;
  half8 v;
#pragma unroll
  for (int j = 0; j < 8; ++j) v[j] = (_Float16)W[(size_t)(kb + j) * HID + n];
  *(half8*)(Bp + (((size_t)(blockIdx.z * 8 + tn) * KS + ks) * 64 + lane) * 8) = v;
}

// ---------------- cvt helper: pack two fp32 -> fp16x2 (RTZ), as half2t --------------
__device__ inline half2t cvt_pk(float a, float b) {
  fp16x2 r = __builtin_amdgcn_cvt_pkrtz(a, b);
  union { fp16x2 f; half2t h; } c;
  c.f = r;
  return c.h;
}

// ===== blocked output layout (both GEMMs): =====
//   y part (cols 0..127):   C[((g*M + row)*16 + lm]          g = col>>4
//   z part (cols 128..255): C[M*128 + ((g*M + row)*16 + lm]  g = (col-128)>>4
// Each column group g is a contiguous M x 32B slab (3.2 MB at M=100k) that fits a
// single XCD's 4 MB L2 (verified round 1: FETCH 366->80 MB with g = blockIdx&7 pin).

// ---------------- GEMM (fp32 A): C = A[M x 384] @ [Bl | Br] ----------------
__global__ __launch_bounds__(512) void gemm_f32a(
    const float* __restrict__ A, int M,
    const _Float16* __restrict__ Bp, _Float16* __restrict__ C) {
  __shared__ float As[128 * 32];   // (row*8 + cg_phys)*4 floats, cg_phys = cg ^ (row&7)

  const int K = IN_DIM, KS = IN_DIM / 32;
  const int tid = threadIdx.x;
  const int lane = tid & 63;
  const int wid = tid >> 6;
  const int quad = lane >> 4;
  const int lm = lane & 15;
  const int row0 = (wid & 1) * 64;
  const int ct0 = (wid >> 1) * 4;
  const int blockRow = blockIdx.x * 128;

  const int srow = lane >> 3;
  const int scol = ((lane & 7) ^ (srow & 7)) * 4;
  const int grow0 = min(blockRow + wid * 16 + srow, M - 1);
  const int grow1 = min(blockRow + wid * 16 + 8 + srow, M - 1);

  floatx4 acc[16];
#pragma unroll
  for (int i = 0; i < 16; ++i) {
    acc[i][0] = 0.f; acc[i][1] = 0.f; acc[i][2] = 0.f; acc[i][3] = 0.f;
  }

  for (int ks = 0; ks < KS; ++ks) {
    const int k0 = ks * 32;
    __syncthreads();
    __builtin_amdgcn_global_load_lds(
        (const AS1 void*)(A + (size_t)grow0 * K + k0 + scol),
        (AS3 void*)(As + (wid * 16) * 32), 16, 0, 0);
    __builtin_amdgcn_global_load_lds(
        (const AS1 void*)(A + (size_t)grow1 * K + k0 + scol),
        (AS3 void*)(As + (wid * 16 + 8) * 32), 16, 0, 0);

    half8 bf[4];
#pragma unroll
    for (int ct = 0; ct < 4; ++ct)
      bf[ct] = *(const half8*)(Bp + (((size_t)(ct0 + ct) * KS + ks) * 64 + lane) * 8);

    __syncthreads();

    half8 af[4];
#pragma unroll
    for (int rt = 0; rt < 4; ++rt) {
      const int row = row0 + rt * 16 + lm;
      const int sw = row & 7;
      const floatx4 fA = *(const floatx4*)&As[(row * 8 + ((quad * 2) ^ sw)) * 4];
      const floatx4 fB = *(const floatx4*)&As[(row * 8 + ((quad * 2 + 1) ^ sw)) * 4];
      half2t h01 = cvt_pk(fA[0], fA[1]);
      half2t h23 = cvt_pk(fA[2], fA[3]);
      half2t h45 = cvt_pk(fB[0], fB[1]);
      half2t h67 = cvt_pk(fB[2], fB[3]);
      half8 a;
      a[0] = h01[0]; a[1] = h01[1]; a[2] = h23[0]; a[3] = h23[1];
      a[4] = h45[0]; a[5] = h45[1]; a[6] = h67[0]; a[7] = h67[1];
      af[rt] = a;
    }
#pragma unroll
    for (int rt = 0; rt < 4; ++rt)
#pragma unroll
      for (int ct = 0; ct < 4; ++ct)
        acc[rt * 4 + ct] =
            __builtin_amdgcn_mfma_f32_16x16x32_f16(af[rt], bf[ct], acc[rt * 4 + ct], 0, 0, 0);
  }

#pragma unroll
  for (int rt = 0; rt < 4; ++rt) {
#pragma unroll
    for (int r = 0; r < 4; ++r) {
      const int gm = blockRow + row0 + rt * 16 + quad * 4 + r;
      if (gm < M) {
#pragma unroll
        for (int ct = 0; ct < 4; ++ct) {
          const int tn = ct0 + ct;
          _Float16* dst = C + ((size_t)(tn & 7) * M + gm) * 16 + lm;
          if (tn >= 8) dst += (size_t)M * 128;
          *dst = (_Float16)acc[rt * 4 + ct][r];
        }
      }
    }
  }
}

// ---------------- GEMM (fp16 A): C = A[M x 128] @ [Bl | Br] ----------------
__global__ __launch_bounds__(512) void gemm_f16a(
    const _Float16* __restrict__ A, int M,
    const _Float16* __restrict__ Bp, _Float16* __restrict__ C) {
  __shared__ _Float16 As[128 * 32];  // (row*4 + cg_phys)*8 halfs

  const int K = HID, KS = HID / 32;
  const int tid = threadIdx.x;
  const int lane = tid & 63;
  const int wid = tid >> 6;
  const int quad = lane >> 4;
  const int lm = lane & 15;
  const int row0 = (wid & 1) * 64;
  const int ct0 = (wid >> 1) * 4;
  const int blockRow = blockIdx.x * 128;

  const int srow = lane >> 2;
  const int scol = ((lane & 3) ^ ((lane >> 3) & 3)) * 8;
  const int grow = min(blockRow + wid * 16 + srow, M - 1);

  floatx4 acc[16];
#pragma unroll
  for (int i = 0; i < 16; ++i) {
    acc[i][0] = 0.f; acc[i][1] = 0.f; acc[i][2] = 0.f; acc[i][3] = 0.f;
  }

  for (int ks = 0; ks < KS; ++ks) {
    const int k0 = ks * 32;
    __syncthreads();
    __builtin_amdgcn_global_load_lds(
        (const AS1 void*)(A + (size_t)grow * K + k0 + scol),
        (AS3 void*)(As + (wid * 16) * 32), 16, 0, 0);

    half8 bf[4];
#pragma unroll
    for (int ct = 0; ct < 4; ++ct)
      bf[ct] = *(const half8*)(Bp + (((size_t)(ct0 + ct) * KS + ks) * 64 + lane) * 8);

    __syncthreads();

    half8 af[4];
#pragma unroll
    for (int rt = 0; rt < 4; ++rt) {
      const int row = row0 + rt * 16 + lm;
      const int cg = quad ^ ((row >> 1) & 3);
      af[rt] = *(const half8*)&As[(row * 4 + cg) * 8];
    }
#pragma unroll
    for (int rt = 0; rt < 4; ++rt)
#pragma unroll
      for (int ct = 0; ct < 4; ++ct)
        acc[rt * 4 + ct] =
            __builtin_amdgcn_mfma_f32_16x16x32_f16(af[rt], bf[ct], acc[rt * 4 + ct], 0, 0, 0);
  }

#pragma unroll
  for (int rt = 0; rt < 4; ++rt) {
#pragma unroll
    for (int r = 0; r < 4; ++r) {
      const int gm = blockRow + row0 + rt * 16 + quad * 4 + r;
      if (gm < M) {
#pragma unroll
        for (int ct = 0; ct < 4; ++ct) {
          const int tn = ct0 + ct;
          _Float16* dst = C + ((size_t)(tn & 7) * M + gm) * 16 + lm;
          if (tn >= 8) dst += (size_t)M * 128;
          *dst = (_Float16)acc[rt * 4 + ct][r];
        }
      }
    }
  }
}

// ---------------- helpers ----------------
__device__ inline float2 upk(unsigned u) {
  union { unsigned v; _Float16 h[2]; } c; c.v = u;
  return make_float2((float)c.h[0], (float)c.h[1]);
}
__device__ inline half2t as_h2(unsigned u) {
  union { unsigned v; half2t h; } c; c.v = u;
  return c.h;
}
__device__ inline unsigned as_u32(half2t h) {
  union { half2t h; unsigned v; } c; c.h = h;
  return c.v;
}
__device__ inline unsigned pkadd(unsigned a, unsigned b) {
  return as_u32(as_h2(a) + as_h2(b));   // v_pk_add_f16
}
__device__ inline uint2 pkadd2(uint2 a, uint2 b) {
  a.x = pkadd(a.x, b.x); a.y = pkadd(a.y, b.y); return a;
}

// ---------------- core gather (column-split, 16 nodes/wave) ----------------
// lane = ns*4 + cl: 16 node-slots x 4 col-lanes (uint2 = 4 halfs each = 32B/row/group).
// Per 4-edge chunk: 4 idx loads + 4 row loads wave-wide (amortized over 16 groups),
// 4 independent accumulation chains. No cross-slot reduction needed (lane owns cols).
__device__ inline uint2 gather_g16(const unsigned* __restrict__ yg,
                                   const int* __restrict__ ss,
                                   int start, int end, int cl) {
  uint2 A0 = make_uint2(0u, 0u);
  uint2 A1 = make_uint2(0u, 0u);
  uint2 A2 = make_uint2(0u, 0u);
  uint2 A3 = make_uint2(0u, 0u);
  int k = start;
  for (; k + 3 < end; k += 4) {
    int s0 = ss[k];
    int s1 = ss[k + 1];
    int s2 = ss[k + 2];
    int s3 = ss[k + 3];
    uint2 v0 = *(const uint2*)(yg + (size_t)s0 * 8 + cl * 2);
    uint2 v1 = *(const uint2*)(yg + (size_t)s1 * 8 + cl * 2);
    uint2 v2 = *(const uint2*)(yg + (size_t)s2 * 8 + cl * 2);
    uint2 v3 = *(const uint2*)(yg + (size_t)s3 * 8 + cl * 2);
    A0 = pkadd2(A0, v0);
    A1 = pkadd2(A1, v1);
    A2 = pkadd2(A2, v2);
    A3 = pkadd2(A3, v3);
  }
  for (; k < end; ++k) {
    uint2 v = *(const uint2*)(yg + (size_t)ss[k] * 8 + cl * 2);
    A0 = pkadd2(A0, v);
  }
  return pkadd2(pkadd2(A0, A1), pkadd2(A2, A3));
}

// ---------------- layer-1 aggregate + combine + ReLU (16 nodes/wave) ----------------
// grid.x = ceil(N/64)*8; g = blockIdx.x & 7 pins each column group to one XCD.
__global__ __launch_bounds__(256) void agg_relu_g16(
    const unsigned* __restrict__ yzu, const int* __restrict__ ss,
    const int* __restrict__ rs, const int* __restrict__ re,
    const float* __restrict__ bias, unsigned* __restrict__ h1u, int N) {
  const int g = blockIdx.x & 7;
  const int w = threadIdx.x >> 6;
  const int lane = threadIdx.x & 63;
  const int cl = lane & 3;
  const int ns = lane >> 2;
  const int node = ((blockIdx.x >> 3) * 4 + w) * 16 + ns;
  const bool active = node < N;
  int start = 0, end = 0;
  if (active) { start = rs[node]; end = re[node]; }
  const unsigned* __restrict__ yg = yzu + (size_t)g * N * 8;
  uint2 A = gather_g16(yg, ss, start, end, cl);
  if (active) {
    const int deg = end - start;
    const float inv = 1.f / (float)max(deg, 1);
    uint2 z2 = *(const uint2*)(yzu + (size_t)N * 64 + ((size_t)g * N + node) * 8 + cl * 2);
    float2 a0 = upk(A.x);
    float2 a1 = upk(A.y);
    float2 z0 = upk(z2.x);
    float2 z1 = upk(z2.y);
    const int c = g * 16 + cl * 4;
    float v0 = fmaxf(a0.x * inv + bias[c]     + z0.x, 0.f);
    float v1 = fmaxf(a0.y * inv + bias[c + 1] + z0.y, 0.f);
    float v2 = fmaxf(a1.x * inv + bias[c + 2] + z1.x, 0.f);
    float v3 = fmaxf(a1.y * inv + bias[c + 3] + z1.y, 0.f);
    union { unsigned v; _Float16 h[2]; } cc;
    uint2 o;
    cc.h[0] = (_Float16)v0; cc.h[1] = (_Float16)v1; o.x = cc.v;
    cc.h[0] = (_Float16)v2; cc.h[1] = (_Float16)v3; o.y = cc.v;
    *(uint2*)(h1u + (size_t)node * 64 + g * 8 + cl * 2) = o;   // h1 row-major
  }
}

// ---------------- layer-2 aggregate + combine + partial scorer dot (16 nodes/wave) ---
__global__ __launch_bounds__(256) void agg_score_g16(
    const unsigned* __restrict__ yzu, const int* __restrict__ ss,
    const int* __restrict__ rs, const int* __restrict__ re,
    const float* __restrict__ bias, const float* __restrict__ Wlin,
    float* __restrict__ sa, float* __restrict__ sb, int N) {
  const int g = blockIdx.x & 7;
  const int w = threadIdx.x >> 6;
  const int lane = threadIdx.x & 63;
  const int cl = lane & 3;
  const int ns = lane >> 2;
  const int node = ((blockIdx.x >> 3) * 4 + w) * 16 + ns;
  const bool active = node < N;
  int start = 0, end = 0;
  if (active) { start = rs[node]; end = re[node]; }
  const unsigned* __restrict__ yg = yzu + (size_t)g * N * 8;
  uint2 A = gather_g16(yg, ss, start, end, cl);
  float pa = 0.f, pb = 0.f;
  if (active) {
    const int deg = end - start;
    const float inv = 1.f / (float)max(deg, 1);
    uint2 z2 = *(const uint2*)(yzu + (size_t)N * 64 + ((size_t)g * N + node) * 8 + cl * 2);
    float2 a0 = upk(A.x);
    float2 a1 = upk(A.y);
    float2 z0 = upk(z2.x);
    float2 z1 = upk(z2.y);
    const int c = g * 16 + cl * 4;
    float h0 = a0.x * inv + bias[c]     + z0.x;
    float h1 = a0.y * inv + bias[c + 1] + z0.y;
    float h2 = a1.x * inv + bias[c + 2] + z1.x;
    float h3 = a1.y * inv + bias[c + 3] + z1.y;
    pa = h0 * Wlin[c] + h1 * Wlin[c + 1] + h2 * Wlin[c + 2] + h3 * Wlin[c + 3];
    pb = h0 * Wlin[128 + c] + h1 * Wlin[129 + c] +
         h2 * Wlin[130 + c] + h3 * Wlin[131 + c];
  }
  // reduce across the 4 cl-lanes of each node-slot (lanes contiguous)
  pa += __shfl_xor(pa, 1, 64); pb += __shfl_xor(pb, 1, 64);
  pa += __shfl_xor(pa, 2, 64); pb += __shfl_xor(pb, 2, 64);
  if (active && cl == 0) {
    atomicAdd(&sa[node], pa);
    atomicAdd(&sb[node], pb);
  }
}

// ---------------- edge scoring (both pos and neg in one launch) ----------------
__global__ void score2(const int* __restrict__ pos, const int* __restrict__ neg,
                       int Ep, int En,
                       const float* __restrict__ sa, const float* __restrict__ sb,
                       const float* __restrict__ blin, float* __restrict__ out) {
  int e = blockIdx.x * 256 + threadIdx.x;
  if (e < Ep) {
    out[e] = sa[pos[e]] + sb[pos[Ep + e]] + blin[0];
  } else if (e < Ep + En) {
    int i = e - Ep;
    out[Ep + i] = sa[neg[i]] + sb[neg[En + i]] + blin[0];
  }
}

extern "C" void kernel_launch(void* const* d_in, const int* in_sizes, int n_in,
                              void* d_out, int out_size, void* d_ws, size_t ws_size,
                              hipStream_t stream) {
  (void)n_in; (void)out_size; (void)ws_size;
  const float* x    = (const float*)d_in[0];
  const int*   ei   = (const int*)d_in[1];
  const int*   pos  = (const int*)d_in[2];
  const int*   neg  = (const int*)d_in[3];
  const float* Wl1  = (const float*)d_in[4];
  const float* bl1  = (const float*)d_in[5];
  const float* Wr1  = (const float*)d_in[6];
  const float* Wl2  = (const float*)d_in[7];
  const float* bl2  = (const float*)d_in[8];
  const float* Wr2  = (const float*)d_in[9];
  const float* Wlin = (const float*)d_in[10];
  const float* blin = (const float*)d_in[11];

  const int N  = in_sizes[0] / IN_DIM;  // 100000
  const int E  = in_sizes[1] / 2;       // 3200000
  const int Ep = in_sizes[2] / 2;       // 500000
  const int En = in_sizes[3] / 2;       // 500000
  const int* e_src = ei;
  const int* e_dst = ei + E;

  char* ws = (char*)d_ws;
  size_t off = 0;
  auto carve = [&](size_t bytes) -> char* {
    char* p = ws + off;
    off += (bytes + 255) & ~(size_t)255;
    return p;
  };
  const int nB = (N + NPB - 1) / NPB;   // 391 buckets
  const int KS1 = IN_DIM / 32;          // 12
  const int KS2 = HID / 32;             // 4

  int*      rs     = (int*)carve((size_t)N * 4);
  int*      re     = (int*)carve((size_t)N * 4);
  int*      bCur   = (int*)carve(512 * 4);
  unsigned* bData  = (unsigned*)carve((size_t)nB * BCAP * 4);
  int*      sorted = (int*)carve((size_t)nB * BCAP * 4);
  float*    sab    = (float*)carve((size_t)2 * N * 4);
  _Float16* Bp1    = (_Float16*)carve((size_t)16 * KS1 * 64 * 8 * 2);
  _Float16* Bp2    = (_Float16*)carve((size_t)16 * KS2 * 64 * 8 * 2);
  _Float16* yz     = (_Float16*)carve((size_t)N * 256 * 2);
  _Float16* h1     = (_Float16*)carve((size_t)N * 128 * 2);

  float* sa = sab;
  float* sb = sab + N;

  const int gemmBlocks = (N + 127) / 128;
  const int partBlocks = (E + 8191) / 8192;  // 391
  const int aggBlocks  = ((N + 63) / 64) * 8;  // 64 nodes/block x 8 column groups

  // CSR build (partition also zero-fills sa/sb for the atomic scorer finish)
  hipLaunchKernelGGL(zero_i32, dim3(2), dim3(256), 0, stream, bCur, 512);
  hipLaunchKernelGGL(partition_kernel, dim3(partBlocks), dim3(512), 0, stream,
                     e_src, e_dst, E, nB, bCur, bData, sab, 2 * N);
  hipLaunchKernelGGL(node_sort3, dim3(nB), dim3(1024), LCAP * 4, stream,
                     bData, bCur, N, sorted, rs, re);

  // weight packing
  hipLaunchKernelGGL(pack_w2, dim3(8, KS1, 2), dim3(64), 0, stream, Wl1, Wr1, Bp1);
  hipLaunchKernelGGL(pack_w2, dim3(8, KS2, 2), dim3(64), 0, stream, Wl2, Wr2, Bp2);

  // layer 1
  hipLaunchKernelGGL(gemm_f32a, dim3(gemmBlocks), dim3(512), 0, stream,
                     x, N, Bp1, yz);
  hipLaunchKernelGGL(agg_relu_g16, dim3(aggBlocks), dim3(256), 0, stream,
                     (const unsigned*)yz, sorted, rs, re, bl1, (unsigned*)h1, N);
  // layer 2
  hipLaunchKernelGGL(gemm_f16a, dim3(gemmBlocks), dim3(512), 0, stream,
                     h1, N, Bp2, yz);
  hipLaunchKernelGGL(agg_score_g16, dim3(aggBlocks), dim3(256), 0, stream,
                     (const unsigned*)yz, sorted, rs, re, bl2, Wlin, sa, sb, N);

  // scoring (single launch)
  float* out = (float*)d_out;
  hipLaunchKernelGGL(score2, dim3((Ep + En + 255) / 256), dim3(256), 0, stream,
                     pos, neg, Ep, En, sa, sb, blin, out);
}

// Round 4
// 716.328 us; speedup vs baseline: 1.0679x; 1.0679x over previous
//
#include <hip/hip_runtime.h>

#define IN_DIM 384
#define HID    128
#define NPB    256            // nodes per bucket (dstLocal fits in 8 bits)
#define BCAP   16384          // fixed bucket capacity (max fill ~8.7k, 1.9x margin)
#define LCAP   10240          // LDS-resident bucket capacity (40KB)

#define AS1 __attribute__((address_space(1)))
#define AS3 __attribute__((address_space(3)))

typedef _Float16 half8 __attribute__((ext_vector_type(8)));
typedef _Float16 half2t __attribute__((ext_vector_type(2)));
typedef __fp16 fp16x2 __attribute__((ext_vector_type(2)));
typedef float floatx4 __attribute__((ext_vector_type(4)));

// ---------------- utility ----------------
__global__ void zero_i32(int* __restrict__ p, int n) {
  int i = blockIdx.x * 256 + threadIdx.x;
  if (i < n) p[i] = 0;
}

// ---------------- phase 1: partition edges into fixed-capacity coarse buckets -------
// 8192 edges/block, 512 threads (8 waves); packed value = (dstLocal << 17) | src
// Also grid-stride zeroes the sa/sb accumulator (needed by agg_score_n4 atomics).
__global__ __launch_bounds__(512) void partition_kernel(
    const int* __restrict__ src, const int* __restrict__ dst, int E, int nB,
    int* __restrict__ bCur, unsigned* __restrict__ bucketData,
    float* __restrict__ sab, int sabN) {
  __shared__ int hist[391];
  __shared__ int gbase[391];
  const int t = threadIdx.x;
  const int b0 = blockIdx.x * 8192;

  for (int i = blockIdx.x * 512 + t; i < sabN; i += gridDim.x * 512) sab[i] = 0.f;

  for (int i = t; i < nB; i += 512) hist[i] = 0;
  __syncthreads();
#pragma unroll
  for (int i = 0; i < 16; ++i) {
    int e = b0 + i * 512 + t;
    if (e < E) atomicAdd(&hist[dst[e] >> 8], 1);
  }
  __syncthreads();
  for (int i = t; i < nB; i += 512) {
    int h = hist[i];
    gbase[i] = h ? (i * BCAP + atomicAdd(&bCur[i], h)) : 0;
    hist[i] = 0;
  }
  __syncthreads();
#pragma unroll
  for (int i = 0; i < 16; ++i) {
    int e = b0 + i * 512 + t;
    if (e < E) {
      int d = dst[e];
      int b = d >> 8;
      int r = atomicAdd(&hist[b], 1);
      bucketData[gbase[b] + r] = ((unsigned)(d & 255) << 17) | (unsigned)src[e];
    }
  }
}

// ---------------- phase 2: per-bucket node histogram + scan + scatter ----------------
__global__ __launch_bounds__(1024) void node_sort3(
    const unsigned* __restrict__ bucketData, const int* __restrict__ bCur,
    int N, int* __restrict__ sorted_src, int* __restrict__ rs, int* __restrict__ re) {
  extern __shared__ unsigned sdata[];          // LCAP entries
  __shared__ int hist[NPB];
  __shared__ int s[NPB];
  __shared__ int cur[NPB];
  const int b = blockIdx.x;
  const int t = threadIdx.x;
  const int start = b * BCAP;
  const int fill = bCur[b];
  if (t < NPB) hist[t] = 0;
  __syncthreads();
  for (int i = t; i < fill; i += 1024) {
    unsigned d = bucketData[start + i];
    if (i < LCAP) sdata[i] = d;
    atomicAdd(&hist[d >> 17], 1);
  }
  __syncthreads();
  int v = 0;
  if (t < NPB) { v = hist[t]; s[t] = v; }
  __syncthreads();
  for (int off = 1; off < NPB; off <<= 1) {
    int y = (t < NPB && t >= off) ? s[t - off] : 0;
    __syncthreads();
    if (t < NPB) s[t] += y;
    __syncthreads();
  }
  if (t < NPB) {
    int excl = s[t] - v;
    const int node = b * NPB + t;
    if (node < N) {
      rs[node] = start + excl;
      re[node] = start + excl + v;
    }
    cur[t] = start + excl;
  }
  __syncthreads();
  for (int i = t; i < fill; i += 1024) {
    unsigned d = (i < LCAP) ? sdata[i] : bucketData[start + i];
    int p = atomicAdd(&cur[d >> 17], 1);
    sorted_src[p] = (int)(d & 0x1FFFF);
  }
}

// ---------------- weight pack: W[K][128] fp32 -> per-lane MFMA B-fragment order ------
__global__ void pack_w2(const float* __restrict__ Wl, const float* __restrict__ Wr,
                        _Float16* __restrict__ Bp) {
  const float* __restrict__ W = blockIdx.z ? Wr : Wl;
  const int tn = blockIdx.x;
  const int ks = blockIdx.y;
  const int KS = gridDim.y;
  const int lane = threadIdx.x;
  const int n = tn * 16 + (lane & 15);
  const int kb = ks * 32 + (lane >> 4) * 8;
  half8 v;
#pragma unroll
  for (int j = 0; j < 8; ++j) v[j] = (_Float16)W[(size_t)(kb + j) * HID + n];
  *(half8*)(Bp + (((size_t)(blockIdx.z * 8 + tn) * KS + ks) * 64 + lane) * 8) = v;
}

// ---------------- cvt helper: pack two fp32 -> fp16x2 (RTZ), as half2t --------------
__device__ inline half2t cvt_pk(float a, float b) {
  fp16x2 r = __builtin_amdgcn_cvt_pkrtz(a, b);
  union { fp16x2 f; half2t h; } c;
  c.f = r;
  return c.h;
}

// ===== blocked output layout (both GEMMs): =====
//   y part (cols 0..127):   C[((g*M + row)*16 + lm]          g = col>>4
//   z part (cols 128..255): C[M*128 + ((g*M + row)*16 + lm]  g = (col-128)>>4
// Each column group g is a contiguous M x 32B slab (3.2 MB at M=100k) that fits a
// single XCD's 4 MB L2 (verified round 1: FETCH 366->80 MB with g = blockIdx&7 pin
// AND short-lived 1-node waves; round 3 showed long-lived multi-node walks thrash it).

// ---------------- GEMM (fp32 A): C = A[M x 384] @ [Bl | Br] ----------------
__global__ __launch_bounds__(512) void gemm_f32a(
    const float* __restrict__ A, int M,
    const _Float16* __restrict__ Bp, _Float16* __restrict__ C) {
  __shared__ float As[128 * 32];   // (row*8 + cg_phys)*4 floats, cg_phys = cg ^ (row&7)

  const int K = IN_DIM, KS = IN_DIM / 32;
  const int tid = threadIdx.x;
  const int lane = tid & 63;
  const int wid = tid >> 6;
  const int quad = lane >> 4;
  const int lm = lane & 15;
  const int row0 = (wid & 1) * 64;
  const int ct0 = (wid >> 1) * 4;
  const int blockRow = blockIdx.x * 128;

  const int srow = lane >> 3;
  const int scol = ((lane & 7) ^ (srow & 7)) * 4;
  const int grow0 = min(blockRow + wid * 16 + srow, M - 1);
  const int grow1 = min(blockRow + wid * 16 + 8 + srow, M - 1);

  floatx4 acc[16];
#pragma unroll
  for (int i = 0; i < 16; ++i) {
    acc[i][0] = 0.f; acc[i][1] = 0.f; acc[i][2] = 0.f; acc[i][3] = 0.f;
  }

  for (int ks = 0; ks < KS; ++ks) {
    const int k0 = ks * 32;
    __syncthreads();
    __builtin_amdgcn_global_load_lds(
        (const AS1 void*)(A + (size_t)grow0 * K + k0 + scol),
        (AS3 void*)(As + (wid * 16) * 32), 16, 0, 0);
    __builtin_amdgcn_global_load_lds(
        (const AS1 void*)(A + (size_t)grow1 * K + k0 + scol),
        (AS3 void*)(As + (wid * 16 + 8) * 32), 16, 0, 0);

    half8 bf[4];
#pragma unroll
    for (int ct = 0; ct < 4; ++ct)
      bf[ct] = *(const half8*)(Bp + (((size_t)(ct0 + ct) * KS + ks) * 64 + lane) * 8);

    __syncthreads();

    half8 af[4];
#pragma unroll
    for (int rt = 0; rt < 4; ++rt) {
      const int row = row0 + rt * 16 + lm;
      const int sw = row & 7;
      const floatx4 fA = *(const floatx4*)&As[(row * 8 + ((quad * 2) ^ sw)) * 4];
      const floatx4 fB = *(const floatx4*)&As[(row * 8 + ((quad * 2 + 1) ^ sw)) * 4];
      half2t h01 = cvt_pk(fA[0], fA[1]);
      half2t h23 = cvt_pk(fA[2], fA[3]);
      half2t h45 = cvt_pk(fB[0], fB[1]);
      half2t h67 = cvt_pk(fB[2], fB[3]);
      half8 a;
      a[0] = h01[0]; a[1] = h01[1]; a[2] = h23[0]; a[3] = h23[1];
      a[4] = h45[0]; a[5] = h45[1]; a[6] = h67[0]; a[7] = h67[1];
      af[rt] = a;
    }
#pragma unroll
    for (int rt = 0; rt < 4; ++rt)
#pragma unroll
      for (int ct = 0; ct < 4; ++ct)
        acc[rt * 4 + ct] =
            __builtin_amdgcn_mfma_f32_16x16x32_f16(af[rt], bf[ct], acc[rt * 4 + ct], 0, 0, 0);
  }

#pragma unroll
  for (int rt = 0; rt < 4; ++rt) {
#pragma unroll
    for (int r = 0; r < 4; ++r) {
      const int gm = blockRow + row0 + rt * 16 + quad * 4 + r;
      if (gm < M) {
#pragma unroll
        for (int ct = 0; ct < 4; ++ct) {
          const int tn = ct0 + ct;
          _Float16* dst = C + ((size_t)(tn & 7) * M + gm) * 16 + lm;
          if (tn >= 8) dst += (size_t)M * 128;
          *dst = (_Float16)acc[rt * 4 + ct][r];
        }
      }
    }
  }
}

// ---------------- GEMM (fp16 A): C = A[M x 128] @ [Bl | Br] ----------------
__global__ __launch_bounds__(512) void gemm_f16a(
    const _Float16* __restrict__ A, int M,
    const _Float16* __restrict__ Bp, _Float16* __restrict__ C) {
  __shared__ _Float16 As[128 * 32];  // (row*4 + cg_phys)*8 halfs

  const int K = HID, KS = HID / 32;
  const int tid = threadIdx.x;
  const int lane = tid & 63;
  const int wid = tid >> 6;
  const int quad = lane >> 4;
  const int lm = lane & 15;
  const int row0 = (wid & 1) * 64;
  const int ct0 = (wid >> 1) * 4;
  const int blockRow = blockIdx.x * 128;

  const int srow = lane >> 2;
  const int scol = ((lane & 3) ^ ((lane >> 3) & 3)) * 8;
  const int grow = min(blockRow + wid * 16 + srow, M - 1);

  floatx4 acc[16];
#pragma unroll
  for (int i = 0; i < 16; ++i) {
    acc[i][0] = 0.f; acc[i][1] = 0.f; acc[i][2] = 0.f; acc[i][3] = 0.f;
  }

  for (int ks = 0; ks < KS; ++ks) {
    const int k0 = ks * 32;
    __syncthreads();
    __builtin_amdgcn_global_load_lds(
        (const AS1 void*)(A + (size_t)grow * K + k0 + scol),
        (AS3 void*)(As + (wid * 16) * 32), 16, 0, 0);

    half8 bf[4];
#pragma unroll
    for (int ct = 0; ct < 4; ++ct)
      bf[ct] = *(const half8*)(Bp + (((size_t)(ct0 + ct) * KS + ks) * 64 + lane) * 8);

    __syncthreads();

    half8 af[4];
#pragma unroll
    for (int rt = 0; rt < 4; ++rt) {
      const int row = row0 + rt * 16 + lm;
      const int cg = quad ^ ((row >> 1) & 3);
      af[rt] = *(const half8*)&As[(row * 4 + cg) * 8];
    }
#pragma unroll
    for (int rt = 0; rt < 4; ++rt)
#pragma unroll
      for (int ct = 0; ct < 4; ++ct)
        acc[rt * 4 + ct] =
            __builtin_amdgcn_mfma_f32_16x16x32_f16(af[rt], bf[ct], acc[rt * 4 + ct], 0, 0, 0);
  }

#pragma unroll
  for (int rt = 0; rt < 4; ++rt) {
#pragma unroll
    for (int r = 0; r < 4; ++r) {
      const int gm = blockRow + row0 + rt * 16 + quad * 4 + r;
      if (gm < M) {
#pragma unroll
        for (int ct = 0; ct < 4; ++ct) {
          const int tn = ct0 + ct;
          _Float16* dst = C + ((size_t)(tn & 7) * M + gm) * 16 + lm;
          if (tn >= 8) dst += (size_t)M * 128;
          *dst = (_Float16)acc[rt * 4 + ct][r];
        }
      }
    }
  }
}

// ---------------- helpers ----------------
__device__ inline float2 upk(unsigned u) {
  union { unsigned v; _Float16 h[2]; } c; c.v = u;
  return make_float2((float)c.h[0], (float)c.h[1]);
}
__device__ inline half2t as_h2(unsigned u) {
  union { unsigned v; half2t h; } c; c.v = u;
  return c.h;
}
__device__ inline unsigned as_u32(half2t h) {
  union { half2t h; unsigned v; } c; c.h = h;
  return c.v;
}
__device__ inline unsigned pkadd(unsigned a, unsigned b) {
  return as_u32(as_h2(a) + as_h2(b));   // v_pk_add_f16
}
__device__ inline uint2 pkadd2(uint2 a, uint2 b) {
  a.x = pkadd(a.x, b.x); a.y = pkadd(a.y, b.y); return a;
}

// ---------------- core gather (column-split, 4 nodes/wave) ----------------
// lane = ns*16 + es*4 + cl: 4 node-slots x 4 edge-slots x 4 col-lanes.
// Each node's edges split over 4 es slots (stride 4), 2-deep unrolled (stride 8).
// Short-lived per-node walks + adjacent-8-blocks-same-nodes keeps the per-XCD
// footprint (3.2 MB slab + ~0.4 MB idx window) inside the 4 MB L2 (round-1 regime).
__device__ inline uint2 gather_n4(const unsigned* __restrict__ yg,
                                  const int* __restrict__ ss,
                                  int start, int end, int es, int cl) {
  uint2 A0 = make_uint2(0u, 0u);
  uint2 A1 = make_uint2(0u, 0u);
  int k = start + es;
  for (; k + 4 < end; k += 8) {
    int s0 = ss[k];
    int s1 = ss[k + 4];
    uint2 v0 = *(const uint2*)(yg + (size_t)s0 * 8 + cl * 2);
    uint2 v1 = *(const uint2*)(yg + (size_t)s1 * 8 + cl * 2);
    A0 = pkadd2(A0, v0);
    A1 = pkadd2(A1, v1);
  }
  if (k < end) {
    uint2 v = *(const uint2*)(yg + (size_t)ss[k] * 8 + cl * 2);
    A0 = pkadd2(A0, v);
  }
  A0 = pkadd2(A0, A1);
  // reduce over the 4 es slots (lanes ns*16 + es*4 + cl; xor bits 2-3)
  uint2 o;
  o.x = (unsigned)__shfl_xor((int)A0.x, 4, 64);
  o.y = (unsigned)__shfl_xor((int)A0.y, 4, 64);
  A0 = pkadd2(A0, o);
  o.x = (unsigned)__shfl_xor((int)A0.x, 8, 64);
  o.y = (unsigned)__shfl_xor((int)A0.y, 8, 64);
  A0 = pkadd2(A0, o);
  return A0;
}

// ---------------- layer-1 aggregate + combine + ReLU (4 nodes/wave) ----------------
// grid.x = ceil(N/16)*8; g = blockIdx.x & 7; adjacent 8 blocks cover the SAME 16
// nodes across the 8 column groups (round-1 co-scheduling property).
__global__ __launch_bounds__(256) void agg_relu_n4(
    const unsigned* __restrict__ yzu, const int* __restrict__ ss,
    const int* __restrict__ rs, const int* __restrict__ re,
    const float* __restrict__ bias, unsigned* __restrict__ h1u, int N) {
  const int g = blockIdx.x & 7;
  const int w = threadIdx.x >> 6;
  const int lane = threadIdx.x & 63;
  const int cl = lane & 3;
  const int es = (lane >> 2) & 3;
  const int ns = lane >> 4;
  const int node = (blockIdx.x >> 3) * 16 + w * 4 + ns;
  const bool active = node < N;
  int start = 0, end = 0;
  if (active) { start = rs[node]; end = re[node]; }
  const unsigned* __restrict__ yg = yzu + (size_t)g * N * 8;
  uint2 A = gather_n4(yg, ss, start, end, es, cl);
  if (active && es == 0) {
    const int deg = end - start;
    const float inv = 1.f / (float)max(deg, 1);
    uint2 z2 = *(const uint2*)(yzu + (size_t)N * 64 + ((size_t)g * N + node) * 8 + cl * 2);
    float2 a0 = upk(A.x);
    float2 a1 = upk(A.y);
    float2 z0 = upk(z2.x);
    float2 z1 = upk(z2.y);
    const int c = g * 16 + cl * 4;
    float v0 = fmaxf(a0.x * inv + bias[c]     + z0.x, 0.f);
    float v1 = fmaxf(a0.y * inv + bias[c + 1] + z0.y, 0.f);
    float v2 = fmaxf(a1.x * inv + bias[c + 2] + z1.x, 0.f);
    float v3 = fmaxf(a1.y * inv + bias[c + 3] + z1.y, 0.f);
    union { unsigned v; _Float16 h[2]; } cc;
    uint2 o;
    cc.h[0] = (_Float16)v0; cc.h[1] = (_Float16)v1; o.x = cc.v;
    cc.h[0] = (_Float16)v2; cc.h[1] = (_Float16)v3; o.y = cc.v;
    *(uint2*)(h1u + (size_t)node * 64 + g * 8 + cl * 2) = o;   // h1 row-major
  }
}

// ---------------- layer-2 aggregate + combine + partial scorer dot (4 nodes/wave) ----
__global__ __launch_bounds__(256) void agg_score_n4(
    const unsigned* __restrict__ yzu, const int* __restrict__ ss,
    const int* __restrict__ rs, const int* __restrict__ re,
    const float* __restrict__ bias, const float* __restrict__ Wlin,
    float* __restrict__ sa, float* __restrict__ sb, int N) {
  const int g = blockIdx.x & 7;
  const int w = threadIdx.x >> 6;
  const int lane = threadIdx.x & 63;
  const int cl = lane & 3;
  const int es = (lane >> 2) & 3;
  const int ns = lane >> 4;
  const int node = (blockIdx.x >> 3) * 16 + w * 4 + ns;
  const bool active = node < N;
  int start = 0, end = 0;
  if (active) { start = rs[node]; end = re[node]; }
  const unsigned* __restrict__ yg = yzu + (size_t)g * N * 8;
  uint2 A = gather_n4(yg, ss, start, end, es, cl);
  float pa = 0.f, pb = 0.f;
  if (active && es == 0) {
    const int deg = end - start;
    const float inv = 1.f / (float)max(deg, 1);
    uint2 z2 = *(const uint2*)(yzu + (size_t)N * 64 + ((size_t)g * N + node) * 8 + cl * 2);
    float2 a0 = upk(A.x);
    float2 a1 = upk(A.y);
    float2 z0 = upk(z2.x);
    float2 z1 = upk(z2.y);
    const int c = g * 16 + cl * 4;
    float h0 = a0.x * inv + bias[c]     + z0.x;
    float h1 = a0.y * inv + bias[c + 1] + z0.y;
    float h2 = a1.x * inv + bias[c + 2] + z1.x;
    float h3 = a1.y * inv + bias[c + 3] + z1.y;
    pa = h0 * Wlin[c] + h1 * Wlin[c + 1] + h2 * Wlin[c + 2] + h3 * Wlin[c + 3];
    pb = h0 * Wlin[128 + c] + h1 * Wlin[129 + c] +
         h2 * Wlin[130 + c] + h3 * Wlin[131 + c];
  }
  // reduce across the 4 cl lanes (xor bits 0-1; es0 quads only exchange within quad)
  pa += __shfl_xor(pa, 1, 64); pb += __shfl_xor(pb, 1, 64);
  pa += __shfl_xor(pa, 2, 64); pb += __shfl_xor(pb, 2, 64);
  if (active && es == 0 && cl == 0) {
    atomicAdd(&sa[node], pa);
    atomicAdd(&sb[node], pb);
  }
}

// ---------------- edge scoring (both pos and neg in one launch) ----------------
__global__ void score2(const int* __restrict__ pos, const int* __restrict__ neg,
                       int Ep, int En,
                       const float* __restrict__ sa, const float* __restrict__ sb,
                       const float* __restrict__ blin, float* __restrict__ out) {
  int e = blockIdx.x * 256 + threadIdx.x;
  if (e < Ep) {
    out[e] = sa[pos[e]] + sb[pos[Ep + e]] + blin[0];
  } else if (e < Ep + En) {
    int i = e - Ep;
    out[Ep + i] = sa[neg[i]] + sb[neg[En + i]] + blin[0];
  }
}

extern "C" void kernel_launch(void* const* d_in, const int* in_sizes, int n_in,
                              void* d_out, int out_size, void* d_ws, size_t ws_size,
                              hipStream_t stream) {
  (void)n_in; (void)out_size; (void)ws_size;
  const float* x    = (const float*)d_in[0];
  const int*   ei   = (const int*)d_in[1];
  const int*   pos  = (const int*)d_in[2];
  const int*   neg  = (const int*)d_in[3];
  const float* Wl1  = (const float*)d_in[4];
  const float* bl1  = (const float*)d_in[5];
  const float* Wr1  = (const float*)d_in[6];
  const float* Wl2  = (const float*)d_in[7];
  const float* bl2  = (const float*)d_in[8];
  const float* Wr2  = (const float*)d_in[9];
  const float* Wlin = (const float*)d_in[10];
  const float* blin = (const float*)d_in[11];

  const int N  = in_sizes[0] / IN_DIM;  // 100000
  const int E  = in_sizes[1] / 2;       // 3200000
  const int Ep = in_sizes[2] / 2;       // 500000
  const int En = in_sizes[3] / 2;       // 500000
  const int* e_src = ei;
  const int* e_dst = ei + E;

  char* ws = (char*)d_ws;
  size_t off = 0;
  auto carve = [&](size_t bytes) -> char* {
    char* p = ws + off;
    off += (bytes + 255) & ~(size_t)255;
    return p;
  };
  const int nB = (N + NPB - 1) / NPB;   // 391 buckets
  const int KS1 = IN_DIM / 32;          // 12
  const int KS2 = HID / 32;             // 4

  int*      rs     = (int*)carve((size_t)N * 4);
  int*      re     = (int*)carve((size_t)N * 4);
  int*      bCur   = (int*)carve(512 * 4);
  unsigned* bData  = (unsigned*)carve((size_t)nB * BCAP * 4);
  int*      sorted = (int*)carve((size_t)nB * BCAP * 4);
  float*    sab    = (float*)carve((size_t)2 * N * 4);
  _Float16* Bp1    = (_Float16*)carve((size_t)16 * KS1 * 64 * 8 * 2);
  _Float16* Bp2    = (_Float16*)carve((size_t)16 * KS2 * 64 * 8 * 2);
  _Float16* yz     = (_Float16*)carve((size_t)N * 256 * 2);
  _Float16* h1     = (_Float16*)carve((size_t)N * 128 * 2);

  float* sa = sab;
  float* sb = sab + N;

  const int gemmBlocks = (N + 127) / 128;
  const int partBlocks = (E + 8191) / 8192;  // 391
  const int aggBlocks  = ((N + 15) / 16) * 8;  // 16 nodes/block x 8 column groups

  // CSR build (partition also zero-fills sa/sb for the atomic scorer finish)
  hipLaunchKernelGGL(zero_i32, dim3(2), dim3(256), 0, stream, bCur, 512);
  hipLaunchKernelGGL(partition_kernel, dim3(partBlocks), dim3(512), 0, stream,
                     e_src, e_dst, E, nB, bCur, bData, sab, 2 * N);
  hipLaunchKernelGGL(node_sort3, dim3(nB), dim3(1024), LCAP * 4, stream,
                     bData, bCur, N, sorted, rs, re);

  // weight packing
  hipLaunchKernelGGL(pack_w2, dim3(8, KS1, 2), dim3(64), 0, stream, Wl1, Wr1, Bp1);
  hipLaunchKernelGGL(pack_w2, dim3(8, KS2, 2), dim3(64), 0, stream, Wl2, Wr2, Bp2);

  // layer 1
  hipLaunchKernelGGL(gemm_f32a, dim3(gemmBlocks), dim3(512), 0, stream,
                     x, N, Bp1, yz);
  hipLaunchKernelGGL(agg_relu_n4, dim3(aggBlocks), dim3(256), 0, stream,
                     (const unsigned*)yz, sorted, rs, re, bl1, (unsigned*)h1, N);
  // layer 2
  hipLaunchKernelGGL(gemm_f16a, dim3(gemmBlocks), dim3(512), 0, stream,
                     h1, N, Bp2, yz);
  hipLaunchKernelGGL(agg_score_n4, dim3(aggBlocks), dim3(256), 0, stream,
                     (const unsigned*)yz, sorted, rs, re, bl2, Wlin, sa, sb, N);

  // scoring (single launch)
  float* out = (float*)d_out;
  hipLaunchKernelGGL(score2, dim3((Ep + En + 255) / 256), dim3(256), 0, stream,
                     pos, neg, Ep, En, sa, sb, blin, out);
}